// Round 2
// 500.138 us; speedup vs baseline: 1.0806x; 1.0806x over previous
//
#include <hip/hip_runtime.h>

// FGPM geometry features: 6 points (x,y) per row -> 15 dists, 20 angles(deg), 20 areas.
// Output layout: out[b*55 + f], f = [dist(15) | angle(20) | area(20)] in
// lexicographic pair/triplet order (i<j<k over 6 keys).
//
// Memory-bound in principle: 96 MB in + 440 MB out (~536 MB -> ~85 us floor at
// 6.3 TB/s). The original writeback was 55 scalar ds_read_b32 + 55 predicated
// dword stores per thread with serial index bookkeeping — issue/latency bound,
// ~2 TB/s effective. This version:
//   * LDS laid out flat [row][55] (row stride 55 floats). Compute-side writes
//     have lane-stride 55 (odd mod 32) -> 2-way bank aliasing = free (m136).
//   * Writeback: block's output span is T*55 = 7040 contiguous floats = 1760
//     float4, 16B-aligned. 13 full ds_read_b128 + global_store_dwordx4(nt)
//     iterations + one 96-lane residual. Zero per-iteration index arithmetic;
//     contiguous-per-lane b128 LDS reads are the conflict-free pattern.
//   * vec4 type is a clang ext_vector (HIP float4 is a class type that
//     __builtin_nontemporal_store rejects).

constexpr int T  = 128;   // threads per block; 2,000,000 % 128 == 0
constexpr int NF = 55;    // features per row

typedef float vfloat4 __attribute__((ext_vector_type(4)));

__global__ __launch_bounds__(T) void fgpm_kernel(
    const float2* __restrict__ p0, const float2* __restrict__ p1,
    const float2* __restrict__ p2, const float2* __restrict__ p3,
    const float2* __restrict__ p4, const float2* __restrict__ p5,
    float* __restrict__ out, int B)
{
    __shared__ __align__(16) float lds[T * NF];
    const int tid = threadIdx.x;
    const long b  = (long)blockIdx.x * T + tid;

    float2 pt[6];
    if (b < (long)B) {
        pt[0] = p0[b]; pt[1] = p1[b]; pt[2] = p2[b];
        pt[3] = p3[b]; pt[4] = p4[b]; pt[5] = p5[b];
    } else {
        #pragma unroll
        for (int i = 0; i < 6; ++i) pt[i] = make_float2(0.f, 0.f);
    }

    float* row = &lds[tid * NF];

    // ---- 15 pairwise distances ----
    {
        int idx = 0;
        #pragma unroll
        for (int i = 0; i < 6; ++i) {
            #pragma unroll
            for (int j = i + 1; j < 6; ++j) {
                float dx = pt[i].x - pt[j].x;
                float dy = pt[i].y - pt[j].y;
                row[idx++] = sqrtf(dx * dx + dy * dy);
            }
        }
    }

    // ---- 20 triplet angles (at middle vertex) + 20 areas ----
    {
        int t = 0;
        #pragma unroll
        for (int i = 0; i < 6; ++i) {
            #pragma unroll
            for (int j = i + 1; j < 6; ++j) {
                #pragma unroll
                for (int k = j + 1; k < 6; ++k) {
                    const float2 P1 = pt[i], P2 = pt[j], P3 = pt[k];
                    float v1x = P1.x - P2.x, v1y = P1.y - P2.y;
                    float v2x = P3.x - P2.x, v2y = P3.y - P2.y;
                    float dot = v1x * v2x + v1y * v2y;
                    float n1  = v1x * v1x + v1y * v1y;
                    float n2  = v2x * v2x + v2y * v2y;
                    float c   = dot / sqrtf(n1 * n2);
                    c = fminf(1.0f, fmaxf(-1.0f, c));
                    row[15 + t] = acosf(c) * 57.29577951308232f;  // degrees
                    float area = 0.5f * fabsf(P1.x * (P2.y - P3.y) +
                                              P2.x * (P3.y - P1.y) +
                                              P3.x * (P1.y - P2.y));
                    row[35 + t] = area;
                    ++t;
                }
            }
        }
    }

    __syncthreads();

    // ---- coalesced float4 transpose writeback ----
    const long blk_start = (long)blockIdx.x * T;   // first row of this block
    float* o = out + blk_start * NF;

    if (blk_start + T <= (long)B) {
        // Full block: T*NF floats = 1760 float4s, flat on both sides.
        const vfloat4* l4 = reinterpret_cast<const vfloat4*>(lds);
        vfloat4*       o4 = reinterpret_cast<vfloat4*>(o);
        constexpr int N4    = T * NF / 4;     // 1760
        constexpr int FULLK = N4 / T;         // 13
        constexpr int RES   = N4 - FULLK * T; // 96
        #pragma unroll
        for (int k = 0; k < FULLK; ++k)
            __builtin_nontemporal_store(l4[tid + k * T], &o4[tid + k * T]);
        if (tid < RES)
            __builtin_nontemporal_store(l4[tid + FULLK * T], &o4[tid + FULLK * T]);
    } else {
        // Partial tail block (not hit for B % T == 0): scalar fallback.
        const int nrows = (int)((long)B - blk_start);
        const int total = nrows * NF;
        for (int g = tid; g < total; g += T)
            __builtin_nontemporal_store(lds[g], &o[g]);
    }
}

extern "C" void kernel_launch(void* const* d_in, const int* in_sizes, int n_in,
                              void* d_out, int out_size, void* d_ws, size_t ws_size,
                              hipStream_t stream) {
    const int B = in_sizes[0] / 2;   // inputs are (B, 2) float32
    const int grid = (B + T - 1) / T;
    fgpm_kernel<<<grid, dim3(T), 0, stream>>>(
        (const float2*)d_in[0], (const float2*)d_in[1], (const float2*)d_in[2],
        (const float2*)d_in[3], (const float2*)d_in[4], (const float2*)d_in[5],
        (float*)d_out, B);
}

// Round 3
// 498.908 us; speedup vs baseline: 1.0833x; 1.0025x over previous
//
#include <hip/hip_runtime.h>

// FGPM geometry features: 6 points (x,y) per row -> 15 dists, 20 angles(deg), 20 areas.
// Output layout: out[b*55 + f], f = [dist(15) | angle(20) | area(20)] in
// lexicographic pair/triplet order (i<j<k over 6 keys).
//
// Memory-bound in principle: 96 MB in + 440 MB out -> ~85 us floor at 6.3 TB/s.
// R2 fixed the writeback (float4 LDS transpose, -40 us). Remaining consumer:
// precise-IEEE VALU chain (20x f32 divide ~12 instr, 20x libm acosf ~40 instr,
// redundant per-triplet diffs). This version cheapens the math:
//   * 15 pair diffs + sq-norms computed once, reused by all 20 triplets
//     (v1 = d(i,j), v2 = -d(j,k); cross product replaces shoelace).
//   * cos = dot * v_rsq_f32(n1*n2)   (kills IEEE divide + guarded sqrt)
//   * acos via 8-term Hastings poly: sqrt(1-|x|)*P(|x|), err <= ~2e-7 rad,
//     exact at x=+-1 after the clamp.
//   * distances via raw v_sqrt_f32.
//   ~1800 -> ~700 VALU instr/row.
// T=64: LDS 14,080 B/block -> 11 blocks/CU (was 5x128-thread = 10 waves/CU).

constexpr int T  = 64;    // threads per block; 2,000,000 % 64 == 0
constexpr int NF = 55;    // features per row

typedef float vfloat4 __attribute__((ext_vector_type(4)));

// pair index for i<j over 6 keys, lexicographic
__host__ __device__ constexpr int PIDX(int i, int j) {
    return 5 * i - (i * (i - 1)) / 2 + (j - i - 1);
}

__device__ __forceinline__ float acos_deg(float x) {
    // x in [-1,1]. Hastings 8-term: acos(ax) = sqrt(1-ax)*P(ax), ax=|x|.
    float ax = fabsf(x);
    float s  = __builtin_amdgcn_sqrtf(1.0f - ax);
    float p  = -0.0012624911f;
    p = fmaf(p, ax,  0.0066700901f);
    p = fmaf(p, ax, -0.0170881256f);
    p = fmaf(p, ax,  0.0308918810f);
    p = fmaf(p, ax, -0.0501743046f);
    p = fmaf(p, ax,  0.0889789874f);
    p = fmaf(p, ax, -0.2145988016f);
    p = fmaf(p, ax,  1.5707963050f);
    float r = s * p * 57.29577951308232f;   // degrees for x >= 0
    return x < 0.0f ? 180.0f - r : r;
}

__global__ __launch_bounds__(T) void fgpm_kernel(
    const float2* __restrict__ p0, const float2* __restrict__ p1,
    const float2* __restrict__ p2, const float2* __restrict__ p3,
    const float2* __restrict__ p4, const float2* __restrict__ p5,
    float* __restrict__ out, int B)
{
    __shared__ __align__(16) float lds[T * NF];
    const int tid = threadIdx.x;
    const long b  = (long)blockIdx.x * T + tid;

    float2 pt[6];
    if (b < (long)B) {
        pt[0] = p0[b]; pt[1] = p1[b]; pt[2] = p2[b];
        pt[3] = p3[b]; pt[4] = p4[b]; pt[5] = p5[b];
    } else {
        #pragma unroll
        for (int i = 0; i < 6; ++i) pt[i] = make_float2(0.f, 0.f);
    }

    float* row = &lds[tid * NF];

    // ---- 15 pair diffs, squared norms, distances ----
    float dx[15], dy[15], nn[15];
    #pragma unroll
    for (int i = 0; i < 6; ++i) {
        #pragma unroll
        for (int j = i + 1; j < 6; ++j) {
            const int q = PIDX(i, j);
            dx[q] = pt[i].x - pt[j].x;
            dy[q] = pt[i].y - pt[j].y;
            nn[q] = fmaf(dx[q], dx[q], dy[q] * dy[q]);
            row[q] = __builtin_amdgcn_sqrtf(nn[q]);
        }
    }

    // ---- 20 triplet angles (at middle vertex j) + 20 areas ----
    // v1 = P1-P2 = d(i,j);  v2 = P3-P2 = -d(j,k)
    {
        int t = 0;
        #pragma unroll
        for (int i = 0; i < 6; ++i) {
            #pragma unroll
            for (int j = i + 1; j < 6; ++j) {
                const int q1 = PIDX(i, j);
                #pragma unroll
                for (int k = j + 1; k < 6; ++k) {
                    const int q2 = PIDX(j, k);
                    float dot = -fmaf(dx[q1], dx[q2], dy[q1] * dy[q2]);
                    float c   = dot * __builtin_amdgcn_rsqf(nn[q1] * nn[q2]);
                    c = fminf(1.0f, fmaxf(-1.0f, c));
                    row[15 + t] = acos_deg(c);
                    float cross = fmaf(dx[q1], dy[q2], -(dy[q1] * dx[q2]));
                    row[35 + t] = 0.5f * fabsf(cross);
                    ++t;
                }
            }
        }
    }

    __syncthreads();

    // ---- coalesced float4 transpose writeback ----
    const long blk_start = (long)blockIdx.x * T;   // first row of this block
    float* o = out + blk_start * NF;

    if (blk_start + T <= (long)B) {
        // Full block: T*NF floats = 880 float4s, flat on both sides.
        const vfloat4* l4 = reinterpret_cast<const vfloat4*>(lds);
        vfloat4*       o4 = reinterpret_cast<vfloat4*>(o);
        constexpr int N4    = T * NF / 4;     // 880
        constexpr int FULLK = N4 / T;         // 13
        constexpr int RES   = N4 - FULLK * T; // 48
        #pragma unroll
        for (int k = 0; k < FULLK; ++k)
            __builtin_nontemporal_store(l4[tid + k * T], &o4[tid + k * T]);
        if (tid < RES)
            __builtin_nontemporal_store(l4[tid + FULLK * T], &o4[tid + FULLK * T]);
    } else {
        // Partial tail block (not hit for B % T == 0): scalar fallback.
        const int nrows = (int)((long)B - blk_start);
        const int total = nrows * NF;
        for (int g = tid; g < total; g += T)
            __builtin_nontemporal_store(lds[g], &o[g]);
    }
}

extern "C" void kernel_launch(void* const* d_in, const int* in_sizes, int n_in,
                              void* d_out, int out_size, void* d_ws, size_t ws_size,
                              hipStream_t stream) {
    const int B = in_sizes[0] / 2;   // inputs are (B, 2) float32
    const int grid = (B + T - 1) / T;
    fgpm_kernel<<<grid, dim3(T), 0, stream>>>(
        (const float2*)d_in[0], (const float2*)d_in[1], (const float2*)d_in[2],
        (const float2*)d_in[3], (const float2*)d_in[4], (const float2*)d_in[5],
        (float*)d_out, B);
}